// Round 10
// baseline (857.040 us; speedup 1.0000x reference)
//
#include <hip/hip_runtime.h>
#include <hip/hip_bf16.h>

// DeformableTransformerDecoderLayer on MI355X — Round 11.
// R10: 842.7 us. val-proj (128x256 tile) still #1 at 144 us: WRITE fixed
// (87 MB = ideal) but Occupancy 34.7% (120 unified regs x 8 waves -> ~1.4
// blocks/CU) leaves the 8 serial K-steps latency-bound; roofline floor ~30us.
// This round: (1) val-proj moves to the lds64 kernel (grid (2,2720)=5440
// blocks, 16 AGPR acc, 15.4 KB LDS -> ~4 blocks/CU); A-read-once is dropped
// (x-adjacent blocks L2-hit the shared A tile). 128x256 kernel retired.
// (2) transpose_v LDS-tiled (64x64): both sides coalesced (old version read
// at 4KB stride = 64 lines/wave-load, ~126 MB line traffic for 3.7 MB).
//   E=256 NH=8 HD=32 NL=4 NP=4 DFFN=1024, nq=900 bs=8 Ls=100 Lv=21760.
//
// Arena (byte offsets), S = 7200*256 = 1,843,200 elems:
//   T5 f32 [S]        @ 0            running tgt | self VT (pre-LN scratch)
//   B1 bf16 [S]       @ 7,372,800    cross VT | deform samp
//   B2 bf16 [2S]      @ 11,059,200   self QK | cross q
//   B3 bf16 [S+64K]   @ 18,432,000   self V | cross KV
//   B4 bf16 [S]       @ 22,249,472   attn out | deform off
//   B5 bf16 [S]       @ 25,935,872   proj out | deform awl
//   VAL bf16 [174080*256] @ 29,622,272   projected value, row = ki*8+b
//   H  bf16 [7200*1024]   @ 118,751,232  FFN hidden
//   FLAG int          @ 133,496,832  detected input dtype (1=f32, 0=bf16)
// NEEDED = 133,496,836 bytes (ws ~713 MB per poison fill size).

typedef __hip_bfloat16 bf16;
typedef __attribute__((ext_vector_type(8))) short short8;
typedef __attribute__((ext_vector_type(4))) float f32x4;

__device__ __forceinline__ float toF(bf16 x) { return __bfloat162float(x); }

__device__ __forceinline__ float ldF(const void* p, size_t i, int f32mode) {
    if (f32mode) return ((const float*)p)[i];
    return __bfloat162float(((const bf16*)p)[i]);
}
__device__ __forceinline__ void stF(void* p, size_t i, int f32mode, float v) {
    if (f32mode) ((float*)p)[i] = v;
    else ((bf16*)p)[i] = __float2bfloat16(v);
}
// mode codes: 0 = bf16 (ws), 1 = f32 (ws), 2 = external (use flag)
__device__ __forceinline__ int decode(int code, int fl) { return code == 2 ? fl : code; }

__device__ __forceinline__ short f2b(float x) {
    bf16 h = __float2bfloat16(x);
    return *(short*)&h;
}

// Load 8 consecutive elements starting at element idx as a bf16x8 fragment.
__device__ __forceinline__ short8 loadFrag8(const void* p, size_t idx, int f32m) {
    short8 r;
    if (f32m) {
        const float4* q = (const float4*)((const float*)p + idx);
        float4 u = q[0];
        float4 v = q[1];
        r[0] = f2b(u.x); r[1] = f2b(u.y); r[2] = f2b(u.z); r[3] = f2b(u.w);
        r[4] = f2b(v.x); r[5] = f2b(v.y); r[6] = f2b(v.z); r[7] = f2b(v.w);
    } else {
        r = *(const short8*)((const bf16*)p + idx);
    }
    return r;
}

// Fused A+R load (R = residual/positional, same [row][256] layout, idx shared).
__device__ __forceinline__ short8 loadFragF(const void* A, size_t ia, int am,
                                            const void* R, int rm) {
    if (R == nullptr) return loadFrag8(A, ia, am);
    short8 o;
#pragma unroll
    for (int j = 0; j < 8; j++) o[j] = f2b(ldF(A, ia + j, am) + ldF(R, ia + j, rm));
    return o;
}

// ---------------------------------------------------------------------------
// Input dtype detector (unchanged).
// ---------------------------------------------------------------------------
__global__ __launch_bounds__(256) void detect_kernel(
    const unsigned short* __restrict__ t, int* __restrict__ flag)
{
    __shared__ int bad;
    if (threadIdx.x == 0) bad = 0;
    __syncthreads();
    int my = 0;
    for (int k = 0; k < 8; k++) {
        unsigned u = t[threadIdx.x + 256 * k];
        unsigned e = (u >> 7) & 0xFF;
        if (e >= 0xC0) my = 1;
    }
    if (my) atomicOr(&bad, 1);
    __syncthreads();
    if (threadIdx.x == 0) *flag = bad;
}

__global__ __launch_bounds__(256) void dbg_kernel(bf16* out, int n, float v)
{
    int i = blockIdx.x * 256 + threadIdx.x;
    if (i < n) out[i] = __float2bfloat16(v);
}

// ---------------------------------------------------------------------------
// LDS-staged MFMA GEMM, 64(M) x 128(N) tile — ALL GEMMs now (incl val-proj).
// 512 thr / 8 waves; wave (wr=w>>1 rows wr*16, wc=w&1 cols wc*64); acc[4]
// (16 AGPR -> high occupancy). Optional fused residual R (A+R staged).
// Grid: (N/128, ceil(M/64)). N % 128 == 0, K % 32 == 0, M arbitrary.
// ---------------------------------------------------------------------------
template <bool RELU>
__global__ __launch_bounds__(512) void mgemm_lds64_kernel(
    const void* __restrict__ A, int lda, size_t aOff, int aCode,
    const void* __restrict__ R, int rCode,
    const void* __restrict__ W, size_t wOff,
    const void* __restrict__ bias, size_t bOff,
    bf16* __restrict__ C, int ldc,
    int M, int K, const int* __restrict__ flagp)
{
    const int fl = *flagp;
    const int am = decode(aCode, fl);
    const int rm = decode(rCode, fl);
    const int tid = threadIdx.x;
    const int lane = tid & 63;
    const int w = tid >> 6;
    const int l15 = lane & 15;
    const int quad = lane >> 4;
    const int wr = w >> 1;            // 0..3 (16-row strips)
    const int wc = w & 1;             // 0..1 (64-col strips)
    const int bm = blockIdx.y * 64;
    const int bn = blockIdx.x * 128;

    __shared__ short Al[64][40];
    __shared__ short Bl[128][40];

    // A: 64x32 = 256 slots (threads 0..255); B: 128x32 = 512 slots (all).
    const int sRow = tid >> 2;          // 0..127
    const int sCb  = (tid & 3) * 8;
    const int gArow = min(bm + (sRow & 63), M - 1);
    const size_t aRowBase = aOff + (size_t)gArow * lda + sCb;
    const size_t wRowBase = wOff + (size_t)(bn + sRow) * K + sCb;

    f32x4 acc[4] = {};

    for (int k0 = 0; k0 < K; k0 += 32) {
        __syncthreads();
        if (tid < 256) {
            *(short8*)&Al[sRow][sCb] = loadFragF(A, aRowBase + k0, am, R, rm);
        }
        *(short8*)&Bl[sRow][sCb] = loadFrag8(W, wRowBase + k0, fl);
        __syncthreads();

        short8 a = *(const short8*)&Al[wr * 16 + l15][quad * 8];
#pragma unroll
        for (int nt = 0; nt < 4; nt++) {
            short8 b = *(const short8*)&Bl[wc * 64 + nt * 16 + l15][quad * 8];
            acc[nt] = __builtin_amdgcn_mfma_f32_16x16x32_bf16(a, b, acc[nt], 0, 0, 0);
        }
    }

#pragma unroll
    for (int r = 0; r < 4; r++) {
        int row = bm + wr * 16 + quad * 4 + r;
        if (row < M) {
#pragma unroll
            for (int nt = 0; nt < 4; nt++) {
                int n = bn + wc * 64 + nt * 16 + l15;
                float v = acc[nt][r] + ldF(bias, bOff + n, fl);
                if (RELU) v = fmaxf(v, 0.f);
                C[(size_t)row * ldc + n] = __float2bfloat16(v);
            }
        }
    }
}

// ---------------------------------------------------------------------------
// Fused residual + LayerNorm over E=256 (unchanged).
// ---------------------------------------------------------------------------
__global__ __launch_bounds__(256) void ln_res_kernel(
    const bf16* __restrict__ A, const void* __restrict__ R, int rCode,
    const void* __restrict__ w, const void* __restrict__ b,
    void* __restrict__ out, int oCode, const int* __restrict__ flagp)
{
    const int fl = *flagp;
    const int rm = decode(rCode, fl);
    const int om = decode(oCode, fl);
    const int r = blockIdx.x, tid = threadIdx.x;
    const size_t o = (size_t)r * 256 + tid;
    float x = toF(A[o]) + ldF(R, o, rm);
    __shared__ float red[256];
    red[tid] = x;
    __syncthreads();
    for (int st = 128; st > 0; st >>= 1) {
        if (tid < st) red[tid] += red[tid + st];
        __syncthreads();
    }
    float mean = red[0] * (1.f / 256.f);
    __syncthreads();
    float dx = x - mean;
    red[tid] = dx * dx;
    __syncthreads();
    for (int st = 128; st > 0; st >>= 1) {
        if (tid < st) red[tid] += red[tid + st];
        __syncthreads();
    }
    float var = red[0] * (1.f / 256.f);
    float y = dx * rsqrtf(var + 1e-5f) * ldF(w, tid, fl) + ldF(b, tid, fl);
    stF(out, o, om, y);
}

// ---------------------------------------------------------------------------
// LDS-tiled V transpose with zero pad: V[(kp,b)][hd] -> VT[(b*256+hd)][lkp].
// 64(kp) x 64(hd) tile per block, one (b, hd-tile, kp-tile) each.
// Reads: 32-lane groups fetch 128B contiguous hd; writes: contiguous kp.
// grid.x = (lkp/64) * 8 * 4. lkp % 64 == 0.
// ---------------------------------------------------------------------------
__global__ __launch_bounds__(256) void transpose_v_tiled_kernel(
    const bf16* __restrict__ V, int vs0, int vs1,
    bf16* __restrict__ VT, int Lk, int lkp)
{
    const int bid = blockIdx.x;      // kpt*32 + b*4 + hdt
    const int kpt = bid >> 5;
    const int b = (bid >> 2) & 7;
    const int hdt = bid & 3;
    const int kp0 = kpt * 64;
    const int hd0 = hdt * 64;
    const int tid = threadIdx.x;
    const int tr = tid >> 6;         // 0..3
    const int tc = tid & 63;         // 0..63

    __shared__ bf16 tile[64][65];

#pragma unroll
    for (int j = 0; j < 16; j++) {
        int kp = kp0 + j * 4 + tr;
        bf16 v = __float2bfloat16(0.f);
        if (kp < Lk) v = V[(size_t)kp * vs0 + (size_t)b * vs1 + hd0 + tc];
        tile[j * 4 + tr][tc] = v;
    }
    __syncthreads();
#pragma unroll
    for (int j = 0; j < 16; j++) {
        int hdl = j * 4 + tr;
        VT[(size_t)(b * 256 + hd0 + hdl) * lkp + kp0 + tc] = tile[tc][hdl];
    }
}

// ---------------------------------------------------------------------------
// MFMA flash attention (unchanged; harness-verified).
// ---------------------------------------------------------------------------
__global__ __launch_bounds__(256) void fattn_kernel(
    const bf16* __restrict__ Q, int qs0, int qs1,
    const bf16* __restrict__ K, int ks0, int ks1,
    const bf16* __restrict__ VT, int lkp,
    bf16* __restrict__ O, int Lk, float scale)
{
    const int bh = blockIdx.x;
    const int b = bh >> 3, h = bh & 7;
    const int qt = blockIdx.y;
    const int tid = threadIdx.x;
    const int w = tid >> 6;
    const int lane = tid & 63;
    const int l15 = lane & 15;
    const int quad = lane >> 4;

    __shared__ short Pl[4][16][72];

    const int q0 = qt * 64 + w * 16;
    const int qr = min(q0 + l15, 899);
    short8 aq = *(const short8*)(Q + (size_t)qr * qs0 + (size_t)b * qs1 + h * 32 + quad * 8);

    f32x4 accO0 = {}, accO1 = {};
    float mrow[4] = {-1e30f, -1e30f, -1e30f, -1e30f};
    float lrow[4] = {0.f, 0.f, 0.f, 0.f};

    const bf16* Kb = K + (size_t)b * ks1 + h * 32 + quad * 8;
    const bf16* VTb = VT + (size_t)(b * 256 + h * 32) * lkp;

    const int nkt = (Lk + 63) >> 6;
    for (int kt = 0; kt < nkt; kt++) {
        const int k0 = kt * 64;
        float sv[4][4];
#pragma unroll
        for (int nt = 0; nt < 4; nt++) {
            int kk = k0 + nt * 16 + l15;
            int krow = min(kk, Lk - 1);
            short8 bk = *(const short8*)(Kb + (size_t)krow * ks0);
            f32x4 z = {};
            f32x4 s = __builtin_amdgcn_mfma_f32_16x16x32_bf16(aq, bk, z, 0, 0, 0);
            bool ok = kk < Lk;
#pragma unroll
            for (int r = 0; r < 4; r++) sv[nt][r] = ok ? s[r] * scale : -1e30f;
        }
        float mnew[4], fr[4];
#pragma unroll
        for (int r = 0; r < 4; r++) {
            float t = fmaxf(fmaxf(sv[0][r], sv[1][r]), fmaxf(sv[2][r], sv[3][r]));
            t = fmaxf(t, __shfl_xor(t, 1));
            t = fmaxf(t, __shfl_xor(t, 2));
            t = fmaxf(t, __shfl_xor(t, 4));
            t = fmaxf(t, __shfl_xor(t, 8));
            mnew[r] = fmaxf(mrow[r], t);
            fr[r] = __expf(mrow[r] - mnew[r]);
            mrow[r] = mnew[r];
        }
#pragma unroll
        for (int r = 0; r < 4; r++) {
            float p0 = __expf(sv[0][r] - mnew[r]);
            float p1 = __expf(sv[1][r] - mnew[r]);
            float p2 = __expf(sv[2][r] - mnew[r]);
            float p3 = __expf(sv[3][r] - mnew[r]);
            int row = quad * 4 + r;
            Pl[w][row][l15]      = f2b(p0);
            Pl[w][row][16 + l15] = f2b(p1);
            Pl[w][row][32 + l15] = f2b(p2);
            Pl[w][row][48 + l15] = f2b(p3);
            float t = p0 + p1 + p2 + p3;
            t += __shfl_xor(t, 1);
            t += __shfl_xor(t, 2);
            t += __shfl_xor(t, 4);
            t += __shfl_xor(t, 8);
            lrow[r] = lrow[r] * fr[r] + t;
            accO0[r] *= fr[r];
            accO1[r] *= fr[r];
        }
#pragma unroll
        for (int kt2 = 0; kt2 < 2; kt2++) {
            short8 pa = *(const short8*)&Pl[w][l15][kt2 * 32 + quad * 8];
            short8 v0 = *(const short8*)(VTb + (size_t)l15 * lkp + k0 + kt2 * 32 + quad * 8);
            short8 v1 = *(const short8*)(VTb + (size_t)(16 + l15) * lkp + k0 + kt2 * 32 + quad * 8);
            accO0 = __builtin_amdgcn_mfma_f32_16x16x32_bf16(pa, v0, accO0, 0, 0, 0);
            accO1 = __builtin_amdgcn_mfma_f32_16x16x32_bf16(pa, v1, accO1, 0, 0, 0);
        }
    }
#pragma unroll
    for (int r = 0; r < 4; r++) {
        int q = q0 + quad * 4 + r;
        if (q < 900) {
            float inv = 1.f / lrow[r];
            size_t o = ((size_t)q * 8 + b) * 256 + h * 32;
            O[o + l15]      = __float2bfloat16(accO0[r] * inv);
            O[o + 16 + l15] = __float2bfloat16(accO1[r] * inv);
        }
    }
}

// ---------------------------------------------------------------------------
// Deformable sampling, all batches, 7200 blocks. VAL rows are [ki*8+b][256]
// (row stride 2048 elems per spatial index; +b*256 base).
// ---------------------------------------------------------------------------
__device__ __forceinline__ float sample_one(const bf16* __restrict__ valb,
                                            int base, int HW, int yi, int xi,
                                            int hd32)
{
    bool valid = (xi >= 0) && (xi < HW) && (yi >= 0) && (yi < HW);
    int ix = min(max(xi, 0), HW - 1);
    int iy = min(max(yi, 0), HW - 1);
    size_t idx = (size_t)(base + iy * HW + ix) * 2048 + hd32;
    float v = toF(valb[idx]);
    return valid ? v : 0.f;
}

__global__ __launch_bounds__(256) void deform_kernel(
    const bf16* __restrict__ val,
    const bf16* __restrict__ off,
    const bf16* __restrict__ awl,
    const void* __restrict__ refp,
    bf16* __restrict__ samp, const int* __restrict__ flagp)
{
    const int fl = *flagp;
    const int levH[4] = {128, 64, 32, 16};
    const int levS[4] = {0, 16384, 20480, 21504};
    const int r = blockIdx.x;
    const int tid = threadIdx.x;
    const int h = tid >> 5, d = tid & 31;
    const int hd32 = h * 32 + d;

    const bf16* valb = val + (size_t)(r & 7) * 256;

    const bf16* lg = awl + (size_t)r * 128 + h * 16;
    float w[16];
    float mx = -1e30f;
#pragma unroll
    for (int i = 0; i < 16; i++) { w[i] = toF(lg[i]); mx = fmaxf(mx, w[i]); }
    float sm = 0.f;
#pragma unroll
    for (int i = 0; i < 16; i++) { w[i] = expf(w[i] - mx); sm += w[i]; }
    float inv = 1.f / sm;

    const bf16* offr = off + (size_t)r * 256 + h * 32;
    float acc = 0.f;
#pragma unroll
    for (int l = 0; l < 4; l++) {
        const int HW = levH[l];
        const int base = levS[l];
        float rx = ldF(refp, (size_t)r * 16 + l * 4 + 0, fl);
        float ry = ldF(refp, (size_t)r * 16 + l * 4 + 1, fl);
        float rw = ldF(refp, (size_t)r * 16 + l * 4 + 2, fl);
        float rh = ldF(refp, (size_t)r * 16 + l * 4 + 3, fl);
#pragma unroll
        for (int p = 0; p < 4; p++) {
            float ox = toF(offr[l * 8 + p * 2 + 0]);
            float oy = toF(offr[l * 8 + p * 2 + 1]);
            float locx = rx + ox * 0.125f * rw;   // off/NP * wh * 0.5
            float locy = ry + oy * 0.125f * rh;
            float x = locx * HW - 0.5f;
            float y = locy * HW - 0.5f;
            float x0f = floorf(x), y0f = floorf(y);
            int x0 = (int)x0f, y0 = (int)y0f;
            float fx = x - x0f, fy = y - y0f;
            float wgt = w[l * 4 + p] * inv;
            float s00 = sample_one(valb, base, HW, y0,     x0,     hd32);
            float s01 = sample_one(valb, base, HW, y0,     x0 + 1, hd32);
            float s10 = sample_one(valb, base, HW, y0 + 1, x0,     hd32);
            float s11 = sample_one(valb, base, HW, y0 + 1, x0 + 1, hd32);
            acc += wgt * (s00 * (1.f - fx) * (1.f - fy) + s01 * fx * (1.f - fy) +
                          s10 * (1.f - fx) * fy + s11 * fx * fy);
        }
    }
    samp[(size_t)r * 256 + tid] = __float2bfloat16(acc);
}

// ---------------------------------------------------------------------------
extern "C" void kernel_launch(void* const* d_in, const int* in_sizes, int n_in,
                              void* d_out, int out_size, void* d_ws, size_t ws_size,
                              hipStream_t stream)
{
    (void)in_sizes; (void)n_in;
    const void* tgt      = d_in[0];
    const void* tgt_pos  = d_in[1];
    const void* refp     = d_in[2];
    const void* mem_sup  = d_in[3];
    const void* memory   = d_in[4];
    const void* sa_in_w  = d_in[6];
    const void* sa_in_b  = d_in[7];
    const void* sa_out_w = d_in[8];
    const void* sa_out_b = d_in[9];
    const void* cs_in_w  = d_in[10];
    const void* cs_in_b  = d_in[11];
    const void* cs_out_w = d_in[12];
    const void* cs_out_b = d_in[13];
    const void* so_w = d_in[14];
    const void* so_b = d_in[15];
    const void* aw_w = d_in[16];
    const void* aw_b = d_in[17];
    const void* vp_w = d_in[18];
    const void* vp_b = d_in[19];
    const void* op_w = d_in[20];
    const void* op_b = d_in[21];
    const void* n1w = d_in[22];
    const void* n1b = d_in[23];
    const void* n2w = d_in[24];
    const void* n2b = d_in[25];
    const void* csnw = d_in[26];
    const void* csnb = d_in[27];
    const void* n3w = d_in[28];
    const void* n3b = d_in[29];
    const void* l1w = d_in[30];
    const void* l1b = d_in[31];
    const void* l2w = d_in[32];
    const void* l2b = d_in[33];

    const int S = 900 * 8 * 256;
    const size_t NEEDED = 133496836;
    const dim3 blk(256);
    const dim3 blk2(512);

    if (ws_size < NEEDED) {
        dbg_kernel<<<(out_size + 255) / 256, blk, 0, stream>>>(
            (bf16*)d_out, out_size, (float)(ws_size >> 20));
        return;
    }

    char* base = (char*)d_ws;
    float* T5 = (float*)base;               // [S] f32
    bf16* B1  = (bf16*)(base + 7372800);    // [S]
    bf16* B2  = (bf16*)(base + 11059200);   // [2S]
    bf16* B3  = (bf16*)(base + 18432000);   // [S + 64K elems]
    bf16* B4  = (bf16*)(base + 22249472);   // [S]
    bf16* B5  = (bf16*)(base + 25935872);   // [S]
    bf16* VAL = (bf16*)(base + 29622272);   // [174080 * 256], row = ki*8+b
    bf16* H   = (bf16*)(base + 118751232);  // [7200 * 1024]
    int* FL   = (int*)(base + 133496832);

    const float scale = 0.1767766953f;  // 1/sqrt(32)
    const int MT = 7200;
    const int gy = 113;  // ceil(7200/64)

    detect_kernel<<<1, blk, 0, stream>>>((const unsigned short*)tgt, FL);

    // ---- self attention (Lk=900, LkPad=960; VT in T5 region, dead pre-LN) ----
    mgemm_lds64_kernel<false><<<dim3(4, gy), blk2, 0, stream>>>(
        tgt, 256, 0, 2, tgt_pos, 2, sa_in_w, 0, sa_in_b, 0,
        B2, 512, MT, 256, FL);                                               // q,k (A=tgt+pos)
    mgemm_lds64_kernel<false><<<dim3(2, gy), blk2, 0, stream>>>(
        tgt, 256, 0, 2, nullptr, 0, sa_in_w, 131072, sa_in_b, 512,
        B3, 256, MT, 256, FL);                                               // v
    transpose_v_tiled_kernel<<<480, blk, 0, stream>>>(
        B3, 2048, 256, (bf16*)T5, 900, 960);
    fattn_kernel<<<dim3(64, 15), blk, 0, stream>>>(
        B2, 4096, 512, B2 + 256, 4096, 512, (bf16*)T5, 960, B4, 900, scale);
    mgemm_lds64_kernel<false><<<dim3(2, gy), blk2, 0, stream>>>(
        B4, 256, 0, 0, nullptr, 0, sa_out_w, 0, sa_out_b, 0,
        B5, 256, MT, 256, FL);
    ln_res_kernel<<<MT, blk, 0, stream>>>(B5, tgt, 2, n2w, n2b, T5, 1, FL);

    // ---- cross attention (memory_support, Lk=100, LkPad=128; VT in B1) ----
    mgemm_lds64_kernel<false><<<dim3(2, gy), blk2, 0, stream>>>(
        T5, 256, 0, 1, tgt_pos, 2, cs_in_w, 0, cs_in_b, 0,
        B2, 256, MT, 256, FL);                                               // q (A=T5+pos)
    mgemm_lds64_kernel<false><<<dim3(4, 13), blk2, 0, stream>>>(
        mem_sup, 256, 0, 2, nullptr, 0, cs_in_w, 65536, cs_in_b, 256,
        B3, 512, 800, 256, FL);                                              // k,v
    transpose_v_tiled_kernel<<<64, blk, 0, stream>>>(
        B3 + 256, 512, 51200, B1, 100, 128);
    fattn_kernel<<<dim3(64, 15), blk, 0, stream>>>(
        B2, 2048, 256, B3, 512, 51200, B1, 128, B4, 100, scale);
    mgemm_lds64_kernel<false><<<dim3(2, gy), blk2, 0, stream>>>(
        B4, 256, 0, 0, nullptr, 0, cs_out_w, 0, cs_out_b, 0,
        B5, 256, MT, 256, FL);
    ln_res_kernel<<<MT, blk, 0, stream>>>(B5, T5, 1, csnw, csnb, T5, 1, FL);

    // ---- deformable attention (query = T5+pos fused into so/aw A-staging) ----
    mgemm_lds64_kernel<false><<<dim3(2, gy), blk2, 0, stream>>>(
        T5, 256, 0, 1, tgt_pos, 2, so_w, 0, so_b, 0,
        B4, 256, MT, 256, FL);                                               // offsets
    mgemm_lds64_kernel<false><<<dim3(1, gy), blk2, 0, stream>>>(
        T5, 256, 0, 1, tgt_pos, 2, aw_w, 0, aw_b, 0,
        B5, 128, MT, 256, FL);                                               // aw logits
    // val proj: memory as flat [174080][256] rows; VAL rows = ki*8+b
    mgemm_lds64_kernel<false><<<dim3(2, 2720), blk2, 0, stream>>>(
        memory, 256, 0, 2, nullptr, 0, vp_w, 0, vp_b, 0,
        VAL, 256, 174080, 256, FL);
    deform_kernel<<<7200, blk, 0, stream>>>(VAL, B4, B5, refp, B1, FL);
    mgemm_lds64_kernel<false><<<dim3(2, gy), blk2, 0, stream>>>(
        B1, 256, 0, 0, nullptr, 0, op_w, 0, op_b, 0,
        B5, 256, MT, 256, FL);                                               // out proj
    ln_res_kernel<<<MT, blk, 0, stream>>>(B5, T5, 1, n1w, n1b, T5, 1, FL);

    // ---- FFN (single-shot via H buffer) ----
    mgemm_lds64_kernel<true><<<dim3(8, gy), blk2, 0, stream>>>(
        T5, 256, 0, 1, nullptr, 0, l1w, 0, l1b, 0, H, 1024, MT, 256, FL);
    mgemm_lds64_kernel<false><<<dim3(2, gy), blk2, 0, stream>>>(
        H, 1024, 0, 0, nullptr, 0, l2w, 0, l2b, 0, B5, 256, MT, 1024, FL);
    ln_res_kernel<<<MT, blk, 0, stream>>>(B5, T5, 1, n3w, n3b, d_out, 2, FL);
}